// Round 5
// baseline (4363.377 us; speedup 1.0000x reference)
//
#include <hip/hip_runtime.h>

typedef __attribute__((ext_vector_type(8))) short short8;
typedef __attribute__((ext_vector_type(4))) float floatx4;

#define T_STEPS 256
#define BATCH   64
#define IDIM    1024
#define HDIM    1024
#define KDIM    (IDIM + HDIM)   // fused [X | H] K dimension
#define MB      16              // batch rows per WG
#define HB      16              // hidden cols per WG (per gate)
#define NWG     256             // 4 batch-groups x 64 h-groups
#define NTHR    512             // 8 waves = 8 K-octants (each does all 4 gates)
#define A_STRIDE (KDIM + 8)     // LDS row stride (+8 elems = 16B pad)

__device__ __forceinline__ unsigned short f2bf(float f) {
  unsigned u = __float_as_uint(f);
  u += 0x7FFFu + ((u >> 16) & 1u);   // round-to-nearest-even
  return (unsigned short)(u >> 16);
}

// Wcat[g][h][k] bf16, k<1024 -> Wx*mx, k>=1024 -> Wh*mh
__global__ void prep_weights(const float* __restrict__ Wx, const float* __restrict__ Wh,
                             const float* __restrict__ mx, const float* __restrict__ mh,
                             unsigned short* __restrict__ Wcat) {
  int idx = blockIdx.x * blockDim.x + threadIdx.x;
  const int total = 4 * HDIM * KDIM / 4;
  if (idx >= total) return;
  int k4 = idx & (KDIM / 4 - 1);
  int gh = idx >> 9;
  int k = k4 * 4;
  float4 v, m;
  if (k < IDIM) {
    v = *(const float4*)(Wx + (size_t)gh * IDIM + k);
    m = *(const float4*)(mx + (size_t)gh * IDIM + k);
  } else {
    v = *(const float4*)(Wh + (size_t)gh * HDIM + (k - IDIM));
    m = *(const float4*)(mh + (size_t)gh * HDIM + (k - IDIM));
  }
  ushort4 o;
  o.x = f2bf(v.x * m.x); o.y = f2bf(v.y * m.y);
  o.z = f2bf(v.z * m.z); o.w = f2bf(v.w * m.w);
  *(ushort4*)(Wcat + (size_t)gh * KDIM + k) = o;
}

// Hpkt layout: [buf:2][bg:4][row:16][col:1024] uint32 packets (tag<<16 | bf16)
__global__ void prep_hpkt(const float* __restrict__ H0, unsigned* __restrict__ Hpkt) {
  int i = blockIdx.x * blockDim.x + threadIdx.x;
  if (i >= BATCH * HDIM) return;
  int b = i >> 10, h = i & 1023;
  int bg = b >> 4, r = b & 15;
  Hpkt[(bg * 16 + r) * 1024 + h] = (unsigned)f2bf(H0[i]);   // buf 0, tag 0
}

__device__ __forceinline__ int tagok(uint4 v, unsigned tagw) {
  return (v.x >> 16) == tagw && (v.y >> 16) == tagw &&
         (v.z >> 16) == tagw && (v.w >> 16) == tagw;
}

__global__ void __launch_bounds__(NTHR, 2)
lstm_main(const float* __restrict__ X,            // [T][B][I] f32
          const float* __restrict__ bias,          // [4][H] f32
          const float* __restrict__ C0,            // [B][H] f32
          const unsigned short* __restrict__ Wcat, // [4][H][K] bf16
          unsigned* __restrict__ Hpkt,             // [2][4][16][1024] packets
          float* __restrict__ out)                 // [T][B][H] f32
{
  __shared__ __align__(16) unsigned short Ash[MB * A_STRIDE];  // 65792 B
  __shared__ float parts[2][4][MB][HB + 1];                    // 8704 B double-buffered

  const int tid  = threadIdx.x;
  const int wg   = blockIdx.x;
  const int bg   = wg >> 6;
  const int hg   = wg & 63;
  const int b0   = bg * MB;
  const int h0   = hg * HB;

  const int w    = tid >> 6;       // wave = K-octant 0..7
  const int lane = tid & 63;
  const int nl   = lane & 15;
  const int quad = lane >> 4;

  // ---- persistent B fragments: Bfr[g][ks] covers k = w*256 + ks*32 + quad*8 .. +8
  short8 Bfr[4][8];
  {
    const short8* wp = (const short8*)Wcat;
#pragma unroll
    for (int g = 0; g < 4; ++g) {
      const int rowbase = (g * HDIM + h0 + nl) * (KDIM / 8);
#pragma unroll
      for (int ks = 0; ks < 8; ++ks)
        Bfr[g][ks] = wp[rowbase + w * 32 + ks * 4 + quad];
    }
  }

  // ---- per-thread cell state (threads 0..255 own a (b,h) cell)
  float c_state = 0.f;
  const int eb = tid >> 4;
  const int eh = tid & 15;
  if (tid < 256) c_state = C0[(b0 + eb) * HDIM + h0 + eh];

  // ---- bias pre-init entries for parts (2 per thread), layout [4][16][17]
  const int e0 = tid, e1 = tid + NTHR;
  const int p0 = (e0 >> 8) * (MB * (HB + 1)) + ((e0 >> 4) & 15) * (HB + 1) + (e0 & 15);
  const int p1 = (e1 >> 8) * (MB * (HB + 1)) + ((e1 >> 4) & 15) * (HB + 1) + (e1 & 15);
  const float binit0 = bias[(e0 >> 8) * HDIM + h0 + (e0 & 15)];
  const float binit1 = bias[(e1 >> 8) * HDIM + h0 + (e1 & 15)];

  // ---- consumer packet offsets (dwords within a [bg][16][1024] region)
  int coff[8];
#pragma unroll
  for (int it = 0; it < 8; ++it) {
    int q = it * NTHR + tid;
    coff[it] = (q >> 8) * 1024 + (q & 255) * 4;
  }

  // ---- preload X slice for t=0 into registers
  float4 Xpre[8];
  {
    const float4* xp = (const float4*)(X + (size_t)b0 * IDIM);
#pragma unroll
    for (int it = 0; it < 8; ++it) {
      int v = it * NTHR + tid;
      Xpre[it] = xp[(v >> 8) * (IDIM / 4) + (v & 255)];
    }
  }

  for (int t = 0; t < T_STEPS; ++t) {
    float* pcur = &parts[t & 1][0][0][0];

    // 1. X regs -> LDS bf16 + bias init
#pragma unroll
    for (int it = 0; it < 8; ++it) {
      int v = it * NTHR + tid;
      int m = v >> 8, c4 = v & 255;
      float4 f = Xpre[it];
      ushort4 o;
      o.x = f2bf(f.x); o.y = f2bf(f.y); o.z = f2bf(f.z); o.w = f2bf(f.w);
      *(ushort4*)&Ash[m * A_STRIDE + c4 * 4] = o;
    }
    pcur[p0] = binit0;
    pcur[p1] = binit1;

    // 2. H packet gather: tag-embedded, flag+data fused, one round trip.
    //    CRITICAL: every load shares an asm block with the s_waitcnt that
    //    covers it, so the compiler can never copy a dst reg before data lands.
    const unsigned* bp = Hpkt + (((unsigned)t & 1u) * 4 + bg) * 16384;
    const unsigned tagw = (unsigned)t;
    uint4 P[8];
    {
      const unsigned *a0 = bp + coff[0], *a1 = bp + coff[1],
                     *a2 = bp + coff[2], *a3 = bp + coff[3],
                     *a4 = bp + coff[4], *a5 = bp + coff[5],
                     *a6 = bp + coff[6], *a7 = bp + coff[7];
      asm volatile(
        "global_load_dwordx4 %0, %8, off sc0 sc1\n\t"
        "global_load_dwordx4 %1, %9, off sc0 sc1\n\t"
        "global_load_dwordx4 %2, %10, off sc0 sc1\n\t"
        "global_load_dwordx4 %3, %11, off sc0 sc1\n\t"
        "global_load_dwordx4 %4, %12, off sc0 sc1\n\t"
        "global_load_dwordx4 %5, %13, off sc0 sc1\n\t"
        "global_load_dwordx4 %6, %14, off sc0 sc1\n\t"
        "global_load_dwordx4 %7, %15, off sc0 sc1\n\t"
        "s_waitcnt vmcnt(0)"
        : "=&v"(P[0]), "=&v"(P[1]), "=&v"(P[2]), "=&v"(P[3]),
          "=&v"(P[4]), "=&v"(P[5]), "=&v"(P[6]), "=&v"(P[7])
        : "v"(a0), "v"(a1), "v"(a2), "v"(a3),
          "v"(a4), "v"(a5), "v"(a6), "v"(a7)
        : "memory");
    }
    unsigned pend = 0u;
#pragma unroll
    for (int it = 0; it < 8; ++it)
      if (!tagok(P[it], tagw)) pend |= 1u << it;
    while (__any(pend != 0u)) {
      __builtin_amdgcn_s_sleep(2);
#pragma unroll
      for (int it = 0; it < 8; ++it) {
        if (pend & (1u << it)) {
          const unsigned* pa = bp + coff[it];
          asm volatile("global_load_dwordx4 %0, %1, off sc0 sc1\n\t"
                       "s_waitcnt vmcnt(0)"
                       : "=&v"(P[it]) : "v"(pa) : "memory");
          if (tagok(P[it], tagw)) pend &= ~(1u << it);
        }
      }
    }

    // 3. packet payloads -> LDS
#pragma unroll
    for (int it = 0; it < 8; ++it) {
      int q = it * NTHR + tid;
      int r = q >> 8, c4 = q & 255;
      uint2 d;
      d.x = (P[it].x & 0xFFFFu) | (P[it].y << 16);
      d.y = (P[it].z & 0xFFFFu) | (P[it].w << 16);
      *(uint2*)&Ash[r * A_STRIDE + IDIM + c4 * 4] = d;
    }
    __syncthreads();

    // 4. prefetch X slice for t+1 (hidden under MFMA/reduce/elementwise)
    {
      int tn = (t + 1 < T_STEPS) ? t + 1 : t;
      const float4* xp = (const float4*)(X + ((size_t)tn * BATCH + b0) * IDIM);
#pragma unroll
      for (int it = 0; it < 8; ++it) {
        int v = it * NTHR + tid;
        Xpre[it] = xp[(v >> 8) * (IDIM / 4) + (v & 255)];
      }
    }

    // 5. MFMA: this wave's K-octant, all 4 gates (A-frag read once, used 4x)
    floatx4 acc[4];
#pragma unroll
    for (int g = 0; g < 4; ++g) acc[g] = floatx4{0.f, 0.f, 0.f, 0.f};
    {
      const unsigned short* abase = &Ash[nl * A_STRIDE + w * 256 + quad * 8];
#pragma unroll
      for (int ks = 0; ks < 8; ++ks) {
        short8 af = *(const short8*)(abase + ks * 32);
#pragma unroll
        for (int g = 0; g < 4; ++g)
          acc[g] = __builtin_amdgcn_mfma_f32_16x16x32_bf16(af, Bfr[g][ks], acc[g], 0, 0, 0);
      }
    }
    // 6. cross-octant reduction (C/D layout: col = lane&15, row = quad*4+reg)
#pragma unroll
    for (int g = 0; g < 4; ++g)
#pragma unroll
      for (int r = 0; r < 4; ++r)
        atomicAdd(&parts[t & 1][g][quad * 4 + r][nl], acc[g][r]);
    __syncthreads();

    // 7. elementwise LSTM update + self-validating packet publish
    if (tid < 256) {
      float gI = parts[t & 1][0][eb][eh];
      float gF = parts[t & 1][1][eb][eh];
      float gO = parts[t & 1][2][eb][eh];
      float gC = parts[t & 1][3][eb][eh];
      float ig = 1.f / (1.f + __expf(-gI));
      float fg = 1.f / (1.f + __expf(-gF));
      float og = 1.f / (1.f + __expf(-gO));
      float cb = 1.f - 2.f / (__expf(2.f * gC) + 1.f);   // tanh, inf-safe
      c_state = fg * c_state + ig * cb;
      float hn = og * (1.f - 2.f / (__expf(2.f * c_state) + 1.f));
      unsigned pkt = ((unsigned)(t + 1) << 16) | (unsigned)f2bf(hn);
      unsigned* dst = Hpkt + ((((unsigned)(t + 1)) & 1u) * 4 + bg) * 16384
                      + eb * 1024 + h0 + eh;
      asm volatile("global_store_dword %0, %1, off sc0 sc1"
                   :: "v"(dst), "v"(pkt) : "memory");
      out[((size_t)t * BATCH + b0 + eb) * HDIM + h0 + eh] = hn;
    }
    // no end-of-step barrier: parts double-buffered, Ash protected by the syncs
  }
}

extern "C" void kernel_launch(void* const* d_in, const int* in_sizes, int n_in,
                              void* d_out, int out_size, void* d_ws, size_t ws_size,
                              hipStream_t stream) {
  const float* X    = (const float*)d_in[0];
  const float* Wx   = (const float*)d_in[1];
  const float* Wh   = (const float*)d_in[2];
  const float* bias = (const float*)d_in[3];
  const float* mx   = (const float*)d_in[4];
  const float* mh   = (const float*)d_in[5];
  const float* H0   = (const float*)d_in[6];
  const float* C0   = (const float*)d_in[7];
  float* out = (float*)d_out;

  unsigned short* Wcat = (unsigned short*)d_ws;                        // 16 MB
  unsigned*       Hpkt = (unsigned*)(Wcat + (size_t)4 * HDIM * KDIM);  // 512 KB

  {
    int tot = 4 * HDIM * KDIM / 4;
    prep_weights<<<(tot + 255) / 256, 256, 0, stream>>>(Wx, Wh, mx, mh, Wcat);
  }
  prep_hpkt<<<(BATCH * HDIM + 255) / 256, 256, 0, stream>>>(H0, Hpkt);

  void* args[] = { (void*)&X, (void*)&bias, (void*)&C0, (void*)&Wcat,
                   (void*)&Hpkt, (void*)&out };
  hipLaunchCooperativeKernel(reinterpret_cast<void*>(lstm_main),
                             dim3(NWG), dim3(NTHR), args, 0, stream);
}

// Round 6
// 3474.896 us; speedup vs baseline: 1.2557x; 1.2557x over previous
//
#include <hip/hip_runtime.h>

typedef __attribute__((ext_vector_type(8))) short short8;
typedef __attribute__((ext_vector_type(4))) float floatx4;

#define T_STEPS 256
#define BATCH   64
#define IDIM    1024
#define HDIM    1024
#define KDIM    (IDIM + HDIM)   // fused [X | H] K dimension
#define MB      16              // batch rows per WG
#define HB      16              // hidden cols per WG (per gate)
#define NWG     256             // 4 batch-groups x 64 h-groups
#define NTHR    512             // 8 waves = 8 K-octants (each does all 4 gates)
#define A_STRIDE (KDIM + 8)     // LDS row stride (+8 elems = 16B pad)

__device__ __forceinline__ unsigned short f2bf(float f) {
  unsigned u = __float_as_uint(f);
  u += 0x7FFFu + ((u >> 16) & 1u);   // round-to-nearest-even
  return (unsigned short)(u >> 16);
}

// Wcat[g][h][k] bf16, k<1024 -> Wx*mx, k>=1024 -> Wh*mh
__global__ void prep_weights(const float* __restrict__ Wx, const float* __restrict__ Wh,
                             const float* __restrict__ mx, const float* __restrict__ mh,
                             unsigned short* __restrict__ Wcat) {
  int idx = blockIdx.x * blockDim.x + threadIdx.x;
  const int total = 4 * HDIM * KDIM / 4;
  if (idx >= total) return;
  int k4 = idx & (KDIM / 4 - 1);
  int gh = idx >> 9;
  int k = k4 * 4;
  float4 v, m;
  if (k < IDIM) {
    v = *(const float4*)(Wx + (size_t)gh * IDIM + k);
    m = *(const float4*)(mx + (size_t)gh * IDIM + k);
  } else {
    v = *(const float4*)(Wh + (size_t)gh * HDIM + (k - IDIM));
    m = *(const float4*)(mh + (size_t)gh * HDIM + (k - IDIM));
  }
  ushort4 o;
  o.x = f2bf(v.x * m.x); o.y = f2bf(v.y * m.y);
  o.z = f2bf(v.z * m.z); o.w = f2bf(v.w * m.w);
  *(ushort4*)(Wcat + (size_t)gh * KDIM + k) = o;
}

// init H0 (bf16) + zero arrival counters
__global__ void prep_h0(const float* __restrict__ H0, unsigned short* __restrict__ Hbuf0,
                        unsigned* __restrict__ cnt) {
  int i = blockIdx.x * blockDim.x + threadIdx.x;
  if (i < BATCH * HDIM) Hbuf0[i] = f2bf(H0[i]);
  if (i < 16 * 16) cnt[i] = 0u;   // 16 sub-counters x 16-dword (64B) lines
}

__global__ void __launch_bounds__(NTHR, 2)
lstm_main(const float* __restrict__ X,            // [T][B][I] f32
          const float* __restrict__ bias,          // [4][H] f32
          const float* __restrict__ C0,            // [B][H] f32
          const unsigned short* __restrict__ Wcat, // [4][H][K] bf16
          unsigned short* __restrict__ Hbuf0,      // [B][H] bf16 double buffer
          unsigned short* __restrict__ Hbuf1,
          unsigned* __restrict__ cnt,              // [4 bg][4 sub] x 16-dword lines
          float* __restrict__ out)                 // [T][B][H] f32
{
  __shared__ __align__(16) unsigned short Ash[MB * A_STRIDE];  // 65792 B
  __shared__ float parts[2][4][MB][HB + 1];                    // 8704 B double-buffered

  const int tid  = threadIdx.x;
  const int wg   = blockIdx.x;
  const int bg   = wg >> 6;
  const int hg   = wg & 63;
  const int b0   = bg * MB;
  const int h0   = hg * HB;

  const int w    = tid >> 6;       // wave = K-octant 0..7
  const int lane = tid & 63;
  const int nl   = lane & 15;
  const int quad = lane >> 4;

  // ---- persistent B fragments: Bfr[g][ks] covers k = w*256 + ks*32 + quad*8 .. +8
  short8 Bfr[4][8];
  {
    const short8* wp = (const short8*)Wcat;
#pragma unroll
    for (int g = 0; g < 4; ++g) {
      const int rowbase = (g * HDIM + h0 + nl) * (KDIM / 8);
#pragma unroll
      for (int ks = 0; ks < 8; ++ks)
        Bfr[g][ks] = wp[rowbase + w * 32 + ks * 4 + quad];
    }
  }

  // ---- per-thread cell state (threads 0..255 own a (b,h) cell)
  float c_state = 0.f;
  const int eb = tid >> 4;
  const int eh = tid & 15;
  if (tid < 256) c_state = C0[(b0 + eb) * HDIM + h0 + eh];

  // ---- bias pre-init entries for parts (2 per thread), layout [4][16][17]
  const int e0 = tid, e1 = tid + NTHR;
  const int p0 = (e0 >> 8) * (MB * (HB + 1)) + ((e0 >> 4) & 15) * (HB + 1) + (e0 & 15);
  const int p1 = (e1 >> 8) * (MB * (HB + 1)) + ((e1 >> 4) & 15) * (HB + 1) + (e1 & 15);
  const float binit0 = bias[(e0 >> 8) * HDIM + h0 + (e0 & 15)];
  const float binit1 = bias[(e1 >> 8) * HDIM + h0 + (e1 & 15)];

  // ---- H-slice load coords (one dwordx4 x 4 rows per thread)
  const int c8 = tid & 127;       // uint4 column 0..127
  const int mrow = tid >> 7;      // 0..3

  unsigned* mycnt  = cnt + (bg * 4 + (hg & 3)) * 16;   // this WG's arrival sub-counter
  unsigned* bgcnt  = cnt + bg * 4 * 16;                // 4 sub-counters of this bg

  // ---- preload X slice for t=0
  float4 Xpre[8];
  {
    const float4* xp = (const float4*)(X + (size_t)b0 * IDIM);
#pragma unroll
    for (int it = 0; it < 8; ++it) {
      int v = it * NTHR + tid;
      Xpre[it] = xp[(v >> 8) * (IDIM / 4) + (v & 255)];
    }
  }

  for (int t = 0; t < T_STEPS; ++t) {
    const unsigned short* __restrict__ Hprev = (t & 1) ? Hbuf1 : Hbuf0;
    unsigned short* __restrict__ Hnext       = (t & 1) ? Hbuf0 : Hbuf1;
    float* pcur = &parts[t & 1][0][0][0];

    // 1. X regs -> LDS bf16 + bias init
#pragma unroll
    for (int it = 0; it < 8; ++it) {
      int v = it * NTHR + tid;
      int m = v >> 8, c4 = v & 255;
      float4 f = Xpre[it];
      ushort4 o;
      o.x = f2bf(f.x); o.y = f2bf(f.y); o.z = f2bf(f.z); o.w = f2bf(f.w);
      *(ushort4*)&Ash[m * A_STRIDE + c4 * 4] = o;
    }
    pcur[p0] = binit0;
    pcur[p1] = binit1;

    // 2. arrival detection: ONE poller per WG on 4 hot cachelines, then barrier C
    if (tid == 0 && t > 0) {
      const unsigned tgt = (unsigned)(64 * t);
      for (;;) {
        unsigned s = __hip_atomic_load(bgcnt +  0, __ATOMIC_RELAXED, __HIP_MEMORY_SCOPE_AGENT)
                   + __hip_atomic_load(bgcnt + 16, __ATOMIC_RELAXED, __HIP_MEMORY_SCOPE_AGENT)
                   + __hip_atomic_load(bgcnt + 32, __ATOMIC_RELAXED, __HIP_MEMORY_SCOPE_AGENT)
                   + __hip_atomic_load(bgcnt + 48, __ATOMIC_RELAXED, __HIP_MEMORY_SCOPE_AGENT);
        if (s >= tgt) break;
        __builtin_amdgcn_s_sleep(8);
      }
    }
    __syncthreads();   // C: releases all threads once data is globally visible

    // 3. H slice: coherent loads (one round trip, loads+waitcnt in ONE asm block)
    {
      const unsigned short* pa = Hprev + (size_t)(b0 + mrow) * HDIM + c8 * 8;
      uint4 d0, d1, d2, d3;
      asm volatile(
        "global_load_dwordx4 %0, %4, off sc0 sc1\n\t"
        "global_load_dwordx4 %1, %5, off sc0 sc1\n\t"
        "global_load_dwordx4 %2, %6, off sc0 sc1\n\t"
        "global_load_dwordx4 %3, %7, off sc0 sc1\n\t"
        "s_waitcnt vmcnt(0)"
        : "=&v"(d0), "=&v"(d1), "=&v"(d2), "=&v"(d3)
        : "v"(pa), "v"(pa + 4 * HDIM), "v"(pa + 8 * HDIM), "v"(pa + 12 * HDIM)
        : "memory");
      *(uint4*)&Ash[(mrow +  0) * A_STRIDE + IDIM + c8 * 8] = d0;
      *(uint4*)&Ash[(mrow +  4) * A_STRIDE + IDIM + c8 * 8] = d1;
      *(uint4*)&Ash[(mrow +  8) * A_STRIDE + IDIM + c8 * 8] = d2;
      *(uint4*)&Ash[(mrow + 12) * A_STRIDE + IDIM + c8 * 8] = d3;
    }
    __syncthreads();   // A: Ash complete

    // 4. prefetch X slice for t+1 (hidden under MFMA/reduce/elementwise)
    {
      int tn = (t + 1 < T_STEPS) ? t + 1 : t;
      const float4* xp = (const float4*)(X + ((size_t)tn * BATCH + b0) * IDIM);
#pragma unroll
      for (int it = 0; it < 8; ++it) {
        int v = it * NTHR + tid;
        Xpre[it] = xp[(v >> 8) * (IDIM / 4) + (v & 255)];
      }
    }

    // 5. MFMA: this wave's K-octant, all 4 gates (A-frag read once, used 4x)
    floatx4 acc[4];
#pragma unroll
    for (int g = 0; g < 4; ++g) acc[g] = floatx4{0.f, 0.f, 0.f, 0.f};
    {
      const unsigned short* abase = &Ash[nl * A_STRIDE + w * 256 + quad * 8];
#pragma unroll
      for (int ks = 0; ks < 8; ++ks) {
        short8 af = *(const short8*)(abase + ks * 32);
#pragma unroll
        for (int g = 0; g < 4; ++g)
          acc[g] = __builtin_amdgcn_mfma_f32_16x16x32_bf16(af, Bfr[g][ks], acc[g], 0, 0, 0);
      }
    }
    // 6. cross-octant reduction (C/D layout: col = lane&15, row = quad*4+reg)
#pragma unroll
    for (int g = 0; g < 4; ++g)
#pragma unroll
      for (int r = 0; r < 4; ++r)
        atomicAdd(&parts[t & 1][g][quad * 4 + r][nl], acc[g][r]);
    __syncthreads();   // B: parts complete

    // 7. elementwise LSTM update + coherent H store
    if (tid < 256) {
      float gI = parts[t & 1][0][eb][eh];
      float gF = parts[t & 1][1][eb][eh];
      float gO = parts[t & 1][2][eb][eh];
      float gC = parts[t & 1][3][eb][eh];
      float ig = 1.f / (1.f + __expf(-gI));
      float fg = 1.f / (1.f + __expf(-gF));
      float og = 1.f / (1.f + __expf(-gO));
      float cb = 1.f - 2.f / (__expf(2.f * gC) + 1.f);   // tanh, inf-safe
      c_state = fg * c_state + ig * cb;
      float hn = og * (1.f - 2.f / (__expf(2.f * c_state) + 1.f));
      unsigned short hb = f2bf(hn);
      unsigned short* ps = Hnext + (size_t)(b0 + eb) * HDIM + h0 + eh;
      asm volatile("global_store_short %0, %1, off sc0 sc1"
                   :: "v"(ps), "v"((unsigned)hb) : "memory");
      out[((size_t)t * BATCH + b0 + eb) * HDIM + h0 + eh] = hn;
    }
    // 8. drain H stores, then ONE arrival increment per WG
    asm volatile("s_waitcnt vmcnt(0)" ::: "memory");
    __syncthreads();   // D: all waves' H stores ack'd at coherence point
    if (tid == 0) atomicAdd(mycnt, 1u);
  }
}

extern "C" void kernel_launch(void* const* d_in, const int* in_sizes, int n_in,
                              void* d_out, int out_size, void* d_ws, size_t ws_size,
                              hipStream_t stream) {
  const float* X    = (const float*)d_in[0];
  const float* Wx   = (const float*)d_in[1];
  const float* Wh   = (const float*)d_in[2];
  const float* bias = (const float*)d_in[3];
  const float* mx   = (const float*)d_in[4];
  const float* mh   = (const float*)d_in[5];
  const float* H0   = (const float*)d_in[6];
  const float* C0   = (const float*)d_in[7];
  float* out = (float*)d_out;

  unsigned short* Wcat  = (unsigned short*)d_ws;                       // 16 MB
  unsigned short* Hbuf0 = Wcat + (size_t)4 * HDIM * KDIM;
  unsigned short* Hbuf1 = Hbuf0 + BATCH * HDIM;
  unsigned*       cnt   = (unsigned*)(Hbuf1 + BATCH * HDIM);           // 1 KB

  {
    int tot = 4 * HDIM * KDIM / 4;
    prep_weights<<<(tot + 255) / 256, 256, 0, stream>>>(Wx, Wh, mx, mh, Wcat);
  }
  prep_h0<<<(BATCH * HDIM + 255) / 256, 256, 0, stream>>>(H0, Hbuf0, cnt);

  void* args[] = { (void*)&X, (void*)&bias, (void*)&C0, (void*)&Wcat,
                   (void*)&Hbuf0, (void*)&Hbuf1, (void*)&cnt, (void*)&out };
  hipLaunchCooperativeKernel(reinterpret_cast<void*>(lstm_main),
                             dim3(NWG), dim3(NTHR), args, 0, stream);
}